// Round 8
// baseline (2985.662 us; speedup 1.0000x reference)
//
#include <hip/hip_runtime.h>

#define E 64
#define D 50
#define SS 384
#define G4 256   // 4*E

__device__ __forceinline__ float fast_rcp(float x){ return __builtin_amdgcn_rcpf(x); }
__device__ __forceinline__ float tanh_fast(float x){
  // tanh(x) = 1 - 2/(exp(2x)+1)
  float e = __expf(2.0f*x);
  return 1.0f - 2.0f*fast_rcp(e + 1.0f);
}
__device__ __forceinline__ float sigmoid_fast(float x){
  return fast_rcp(1.0f + __expf(-x));
}
// whole-wave rotate via DPP (VALU pipe). wave_ror:1: lane i <- lane (i-1)&63.
__device__ __forceinline__ float ror1(float x){
  return __int_as_float(__builtin_amdgcn_update_dpp(
      0, __float_as_int(x), 0x13C /*wave_ror:1*/, 0xF, 0xF, false));
}
__device__ __forceinline__ float rdlane(float v, int l){
  return __int_as_float(__builtin_amdgcn_readlane(__float_as_int(v), l));
}

// ---------------------------------------------------------------------------
// K0: gx[b,s,j] = bias[j] + sum_k emb[sent[b,s],k] * Wih[j,k]   (both LSTMs)
// ---------------------------------------------------------------------------
__global__ __launch_bounds__(256, 1) void gx_kernel(
  const int* __restrict__ sent1, const int* __restrict__ sent2,
  const float* __restrict__ emb,
  const float* __restrict__ Wih1, const float* __restrict__ bih1, const float* __restrict__ bhh1,
  const float* __restrict__ Wih2, const float* __restrict__ bih2, const float* __restrict__ bhh2,
  float* __restrict__ gx1, float* __restrict__ gx2)
{
  const int bb    = blockIdx.x;     // 0..511
  const int which = bb >> 8;
  const int chunk = bb & 255;
  const int j     = threadIdx.x;
  const int*   sent = which ? sent2 : sent1;
  const float* Wih  = which ? Wih2  : Wih1;
  const float* bA   = which ? bih2  : bih1;
  const float* bB   = which ? bhh2  : bhh1;
  float*       gx   = which ? gx2   : gx1;

  float wih[D];
  #pragma unroll
  for (int k=0;k<D;k+=2){
    float2 v = *(const float2*)&Wih[j*D+k];
    wih[k]=v.x; wih[k+1]=v.y;
  }
  const float bias = bA[j] + bB[j];

  __shared__ __align__(16) float xb[8][52];
  const int row0 = chunk*96;
  for (int c=0;c<12;++c){
    const int r0 = row0 + c*8;
    #pragma unroll
    for (int q=0;q<2;++q){
      int tt = j + q*256;
      if (tt < 400){
        int r = tt/50;
        int k = tt - r*50;
        int idx = sent[r0 + r];
        xb[r][k] = emb[(size_t)idx*D + k];
      }
    }
    __syncthreads();
    for (int r=0;r<8;++r){
      float a0=bias, a1=0.f;
      #pragma unroll
      for (int k=0;k<48;k+=4){
        float4 xv = *(const float4*)&xb[r][k];
        a0 += xv.x*wih[k]   + xv.y*wih[k+1];
        a1 += xv.z*wih[k+2] + xv.w*wih[k+3];
      }
      a0 += xb[r][48]*wih[48];
      a1 += xb[r][49]*wih[49];
      gx[(size_t)(r0+r)*G4 + j] = a0+a1;
    }
    __syncthreads();
  }
}

// ---------------------------------------------------------------------------
// K1: both LSTM recurrences. 64 blocks x 256 threads (4 waves).
// DPP rotate-MAC (verified r4).
// ---------------------------------------------------------------------------
__global__ __launch_bounds__(256, 1) void lstm_kernel(
  const float* __restrict__ gx1, const float* __restrict__ gx2,
  const float* __restrict__ Whh1, const float* __restrict__ Whh2,
  const int* __restrict__ s1_len, const int* __restrict__ s2_len,
  float* __restrict__ h1_all, float* __restrict__ out_all,
  float* __restrict__ hn_cap)
{
  const int b = blockIdx.x;
  const int j = threadIdx.x;
  const int lane = j & 63;
  const int wv = j >> 6;
  __shared__ float h_lds[64];
  __shared__ float gates[256];

  float whht[64];                       // whht[i] = Whh[j][(lane-i)&63] (ror direction)
  #pragma unroll
  for (int i=0;i<32;++i){
    whht[i]    = Whh1[j*64 + ((lane-i)&63)];
    whht[i+32] = Whh1[j*64 + ((lane-i+32)&63)];
  }

  const int is_g = (wv==2);             // wave-uniform: gate 'g' uses tanh
  float c_reg=0.f, gh=0.f, gc=0.f, hn=0.f;
  int idx1=0, idx2=0;
  if (j<64){ idx1=s1_len[b*64+j]; idx2=s2_len[b*64+j]; h_lds[j]=0.f; }
  __syncthreads();

  // ---- LSTM1 ----
  {
    const float* gx = gx1 + (size_t)b*SS*G4;
    float* hout = h1_all + (size_t)b*SS*E;
    float gx_cur = gx[j];
    float gx_n1  = gx[G4 + j];
    for (int s=0;s<SS;++s){
      int sn2 = (s+2<SS)? s+2 : SS-1;
      float gx_n2 = gx[(size_t)sn2*G4 + j];
      float hr  = h_lds[lane];          // iter i holds h[(lane-i)&63]
      float hr2 = h_lds[lane^32];       // iter i holds h[(lane-i+32)&63]
      float g0 = gx_cur, g1 = 0.f;
      #pragma unroll
      for (int i=0;i<32;++i){
        g0 = __builtin_fmaf(hr,  whht[i],    g0);
        g1 = __builtin_fmaf(hr2, whht[i+32], g1);
        hr = ror1(hr); hr2 = ror1(hr2);
      }
      float g = g0 + g1;
      gates[j] = is_g ? tanh_fast(g) : sigmoid_fast(g);
      __syncthreads();
      if (j<64){
        float gi=gates[j], gf=gates[64+j], gg=gates[128+j], go=gates[192+j];
        c_reg = gf*c_reg + gi*gg;
        float h = go * tanh_fast(c_reg);
        h_lds[j] = h;
        hout[(size_t)s*E + j] = h;
        if (s==idx1){ gh=h; gc=c_reg; }
      }
      gx_cur = gx_n1; gx_n1 = gx_n2;
      __syncthreads();
    }
  }
  // ---- LSTM2 ----
  #pragma unroll
  for (int i=0;i<32;++i){
    whht[i]    = Whh2[j*64 + ((lane-i)&63)];
    whht[i+32] = Whh2[j*64 + ((lane-i+32)&63)];
  }
  if (j<64){ h_lds[j]=gh; c_reg=gc; }
  __syncthreads();
  {
    const float* gx = gx2 + (size_t)b*SS*G4;
    float* hout = out_all + (size_t)b*SS*E;
    float gx_cur = gx[j];
    float gx_n1  = gx[G4 + j];
    for (int s=0;s<SS;++s){
      int sn2 = (s+2<SS)? s+2 : SS-1;
      float gx_n2 = gx[(size_t)sn2*G4 + j];
      float hr  = h_lds[lane];
      float hr2 = h_lds[lane^32];
      float g0 = gx_cur, g1 = 0.f;
      #pragma unroll
      for (int i=0;i<32;++i){
        g0 = __builtin_fmaf(hr,  whht[i],    g0);
        g1 = __builtin_fmaf(hr2, whht[i+32], g1);
        hr = ror1(hr); hr2 = ror1(hr2);
      }
      float g = g0 + g1;
      gates[j] = is_g ? tanh_fast(g) : sigmoid_fast(g);
      __syncthreads();
      if (j<64){
        float gi=gates[j], gf=gates[64+j], gg=gates[128+j], go=gates[192+j];
        c_reg = gf*c_reg + gi*gg;
        float h = go * tanh_fast(c_reg);
        h_lds[j] = h;
        hout[(size_t)s*E + j] = h;
        if (s==idx2) hn = h;
      }
      gx_cur = gx_n1; gx_n1 = gx_n2;
      __syncthreads();
    }
  }
  if (j<64) hn_cap[b*64+j] = hn;
}

// ---------------------------------------------------------------------------
// K2: 3072 blocks.
//  which==0 (blocks 0..1535):  E_g[row,f] = exp(2*(h1[row]@wy + out[row]@wh)[f])
//  which==1 (blocks 1536..):   Hwr[row,f] = (h1[row]@wr)[f], Hwt = (h1[row]@wt)[f]
// ---------------------------------------------------------------------------
__global__ __launch_bounds__(256, 1) void base_kernel(
  const float* __restrict__ h1_all, const float* __restrict__ out_all,
  const float* __restrict__ wy, const float* __restrict__ wh,
  const float* __restrict__ wr, const float* __restrict__ wt,
  float* __restrict__ E_g, float* __restrict__ Hwr_g, float* __restrict__ Hwt_g)
{
  const int which = (blockIdx.x >= 1536);
  const int blk   = blockIdx.x - (which ? 1536 : 0);
  const int t = threadIdx.x;
  const int wave = t>>6, lane = t&63;
  const float* WA = which ? wr : wy;
  const float* WB = which ? wt : wh;
  float wac[E], wbc[E];
  #pragma unroll
  for (int e=0;e<E;++e){ wac[e]=WA[e*E+lane]; wbc[e]=WB[e*E+lane]; }
  const int row0 = blk*16 + wave*4;
  for (int r=0;r<4;++r){
    int row = row0 + r;
    float hv = h1_all[(size_t)row*E + lane];
    if (which){
      float a0=0,a1=0;
      #pragma unroll
      for (int e=0;e<E;++e){
        float hb = rdlane(hv,e);
        a0 += hb*wac[e];
        a1 += hb*wbc[e];
      }
      Hwr_g[(size_t)row*E + lane] = a0;
      Hwt_g[(size_t)row*E + lane] = a1;
    } else {
      float ov = out_all[(size_t)row*E + lane];
      float a0=0,a1=0;
      #pragma unroll
      for (int e=0;e<E;++e){
        a0 += rdlane(hv,e)*wac[e];
        a1 += rdlane(ov,e)*wbc[e];
      }
      E_g[(size_t)row*E + lane] = __expf(2.0f*(a0+a1));
    }
  }
}

// ---------------------------------------------------------------------------
// K3: attention scan. 64 blocks x 768 threads (12 waves), 384 steps,
// TWO barriers/step. Closed recurrence over (rw = r@wr, ri = r@wt) — r7
// verified. Capture transport FIXED: exCap layout is [b][slot][row] so the
// 6 half==0 waves store CONTIGUOUS 256-B runs (full 64-B lines, no L2
// write-allocate RMW — r7's [row][slot] layout caused 384 partial-line
// HBM round-trips per capture step = the 15.5 MB WRITE_SIZE regression).
// ---------------------------------------------------------------------------
__global__ __launch_bounds__(768, 3) void attn_kernel(
  const float* __restrict__ E_all, const float* __restrict__ Hwr_all,
  const float* __restrict__ Hwt_all,
  const float* __restrict__ w, const float* __restrict__ wr, const float* __restrict__ wt,
  const float* __restrict__ s1_s, const int* __restrict__ s2_len,
  float* __restrict__ exCapT,    // [b][slot<=63][row]  (coalesced stores)
  float* __restrict__ TCap)      // [b][slot][lane]
{
  const int b = blockIdx.x;
  const int t = threadIdx.x;
  const int wv = t>>6, lane = t&63;
  const int pair = wv>>1;          // 0..5: row group
  const int half = wv&1;           // e-range half
  const int off  = half*32;
  const int row  = pair*64 + lane;

  __shared__ float4 accP[12*64];   // {chainWr, chainWt, tot, -} per wave
  __shared__ float2 tgP[2][12*64]; // {T@wr partial, T@wt partial} per wave
  __shared__ float  scoreH[2][6*64];
  __shared__ unsigned int umask[12];

  const float* Eb   = E_all   + (size_t)b*SS*E;
  const float* HwrB = Hwr_all + (size_t)b*SS*E;
  const float* HwtB = Hwt_all + (size_t)b*SS*E;
  float* exCapB = exCapT + (size_t)b*64*SS;  // slot*SS + row
  float* TCapB  = TCap   + (size_t)b*64*64;  // slot*64 + lane

  // ---- preload (once) ----
  float Ee[32];                    // E[row][off..off+32)
  #pragma unroll
  for (int k=0;k<32;k+=4){
    float4 v = *(const float4*)&Eb[(size_t)row*E + off + k];
    Ee[k]=v.x; Ee[k+1]=v.y; Ee[k+2]=v.z; Ee[k+3]=v.w;
  }
  float htWr[32], htWt[32];        // rotate-chain tables (r6-verified pattern)
  #pragma unroll
  for (int i=0;i<32;++i){
    int rr = pair*64 + ((lane-i+off)&63);
    htWr[i] = HwrB[(size_t)rr*E + lane];
    htWt[i] = HwtB[(size_t)rr*E + lane];
  }
  float WSUM = 0.f;
  for (int e=0;e<64;++e) WSUM += w[e];     // uniform -> scalar
  const float s1v = s1_s[b*SS + row];
  const int  idx2 = s2_len[b*E + lane];
  // GEMV k-chunk for this wave (T@wr, T@wt): 4x6 + 8x5 = 64
  const int k0  = (wv<4)? wv*6 : 24+(wv-4)*5;
  const int cnt = (wv<4)? 6 : 5;
  float wrch[6], wtch[6];
  #pragma unroll
  for (int jj=0;jj<6;++jj){
    int kk = k0 + ((jj<cnt)? jj : 0);
    wrch[jj] = wr[kk*E + lane];
    wtch[jj] = wt[kk*E + lane];
  }

  // ---- init: r0 = 0 -> chains 0, tot 1 (one wave), tgP[0] = 0; mask ----
  accP[wv*64+lane] = make_float4(0.f, 0.f, (wv==0)?1.f:0.f, 0.f);
  tgP[0][wv*64+lane] = make_float2(0.f, 0.f);
  if (t<12) umask[t] = 0u;
  __syncthreads();
  if (wv==0) atomicOr(&umask[idx2>>5], 1u<<(idx2&31));
  __syncthreads();

  int slot = 0;
  for (int s=0;s<SS;++s){
    const bool need = (umask[s>>5]>>(s&31)) & 1u;

    // ---- phase 1: combine prev partials; score-half; T-GEMV ----
    float cWr=0.f, cWt=0.f, tot=0.f;
    #pragma unroll
    for (int q=0;q<12;++q){
      float4 v = accP[q*64+lane];
      cWr+=v.x; cWt+=v.y; tot+=v.z;
    }
    float twr=0.f, twt=0.f;
    #pragma unroll
    for (int q=0;q<12;++q){
      float2 v = tgP[s&1][q*64+lane];
      twr+=v.x; twt+=v.y;
    }
    float inv = fast_rcp(tot);
    float rw = __builtin_fmaf(cWr, inv, twr);   // rw[e=lane]
    float ri = __builtin_fmaf(cWt, inv, twt);   // ri[e=lane]
    float Rl = __expf(2.0f*rw);
    float T  = tanh_fast(ri);
    if (need && wv==0) TCapB[slot*64 + lane] = T;

    // score-half (r6-verified loop)
    float sc0=0.f, sc1=0.f, sc2=0.f, sc3=0.f;
    #pragma unroll
    for (int k=0;k<32;k+=4){
      float r0=rdlane(Rl,off+k),   r1=rdlane(Rl,off+k+1);
      float r2=rdlane(Rl,off+k+2), r3=rdlane(Rl,off+k+3);
      sc0 = __builtin_fmaf(w[off+k],   fast_rcp(__builtin_fmaf(Ee[k],  r0,1.f)), sc0);
      sc1 = __builtin_fmaf(w[off+k+1], fast_rcp(__builtin_fmaf(Ee[k+1],r1,1.f)), sc1);
      sc2 = __builtin_fmaf(w[off+k+2], fast_rcp(__builtin_fmaf(Ee[k+2],r2,1.f)), sc2);
      sc3 = __builtin_fmaf(w[off+k+3], fast_rcp(__builtin_fmaf(Ee[k+3],r3,1.f)), sc3);
    }
    float myh = (sc0+sc1)+(sc2+sc3);
    scoreH[half][pair*64+lane] = myh;

    // T-GEMV partials for NEXT step (input T known now)
    {
      float rwp=0.f, rtp=0.f;
      #pragma unroll
      for (int jj=0;jj<6;++jj){
        if (jj<cnt){
          float rv = rdlane(T, k0+jj);
          rwp = __builtin_fmaf(rv, wrch[jj], rwp);
          rtp = __builtin_fmaf(rv, wtch[jj], rtp);
        }
      }
      tgP[(s+1)&1][wv*64+lane] = make_float2(rwp, rtp);
    }
    __syncthreads();

    // ---- phase 2: combine halves; ex; dual rotate-MAC chain ----
    float oth = scoreH[1-half][pair*64+lane];
    float sc = WSUM - 2.0f*(myh + oth);
    float masked = s1v*sc - (1.f - s1v)*1e12f;
    float ex = __expf(masked);
    if (need && half==0) exCapB[(size_t)slot*SS + row] = ex;  // coalesced

    float exr = half ? __shfl_xor(ex, 32) : ex;
    float aWr=0.f, aWt=0.f, at=0.f;
    #pragma unroll
    for (int i=0;i<32;++i){
      aWr = __builtin_fmaf(exr, htWr[i], aWr);
      aWt = __builtin_fmaf(exr, htWt[i], aWt);
      at += exr;
      exr = ror1(exr);
    }
    accP[wv*64+lane] = make_float4(aWr, aWt, at, 0.f);
    __syncthreads();

    slot += need ? 1 : 0;
  }
}

// ---------------------------------------------------------------------------
// K3b: capfix. 64 blocks x 256 threads. rn[lane] = (sum_row ex*h1)/tot + T.
// Transposes exCap[slot][rows] through padded LDS: coalesced float4 global
// loads; per-lane gather at slot c is conflict-free via stride 129.
// ---------------------------------------------------------------------------
__global__ __launch_bounds__(256, 1) void capfix_kernel(
  const float* __restrict__ h1_all, const int* __restrict__ s2_len,
  const float* __restrict__ exCapT, const float* __restrict__ TCap,
  float* __restrict__ rn_cap)
{
  const int b = blockIdx.x, t = threadIdx.x;
  const int wv = t>>6, lane = t&63;
  __shared__ unsigned int umask[12];
  __shared__ float exL[64*129];       // [slot][row-in-chunk], pad 129
  __shared__ float2 part[4][64];
  if (t<12) umask[t]=0u;
  __syncthreads();
  const int sl = s2_len[b*E + lane];
  if (wv==0) atomicOr(&umask[sl>>5], 1u<<(sl&31));
  __syncthreads();
  int c = 0;
  #pragma unroll
  for (int wdi=0; wdi<12; ++wdi){
    unsigned int wd = umask[wdi];
    unsigned int keep = (wdi < (sl>>5)) ? wd
                       : ((wdi == (sl>>5)) ? (wd & ((sl&31) ? ((1u<<(sl&31))-1u) : 0u)) : 0u);
    c += __popc(keep);
  }
  const float* h1b = h1_all + (size_t)b*SS*E;
  const float* exB = exCapT + (size_t)b*64*SS;
  float pa=0.f, pt=0.f;
  for (int chunk=0; chunk<3; ++chunk){
    const int base = chunk*128;
    // coalesced: exB[slot][base..base+127] -> exL[slot][r]
    for (int i=t; i<64*32; i+=256){
      int slot = i>>5;
      int r4   = (i&31)*4;
      float4 v = *(const float4*)&exB[(size_t)slot*SS + base + r4];
      exL[slot*129 + r4+0]=v.x; exL[slot*129 + r4+1]=v.y;
      exL[slot*129 + r4+2]=v.z; exL[slot*129 + r4+3]=v.w;
    }
    __syncthreads();
    const int woff = wv*32;
    #pragma unroll
    for (int i=0;i<32;++i){
      int r = woff + i;
      float exv = exL[c*129 + r];
      float hv  = h1b[(size_t)(base+r)*E + lane];
      pa = __builtin_fmaf(exv, hv, pa);
      pt += exv;
    }
    __syncthreads();
  }
  part[wv][lane] = make_float2(pa, pt);
  __syncthreads();
  if (wv==0){
    float av=0.f, tv=0.f;
    #pragma unroll
    for (int q=0;q<4;++q){ float2 v=part[q][lane]; av+=v.x; tv+=v.y; }
    rn_cap[b*E+lane] = av*fast_rcp(tv) + TCap[(size_t)b*64*64 + c*64 + lane];
  }
}

// ---------------------------------------------------------------------------
// K4: final MLP. 64 blocks x 128 threads.
// ---------------------------------------------------------------------------
__global__ __launch_bounds__(128, 1) void final_kernel(
  const float* __restrict__ rn_cap, const float* __restrict__ hn_cap,
  const float* __restrict__ wp, const float* __restrict__ wx,
  const float* __restrict__ l1W, const float* __restrict__ l1b,
  const float* __restrict__ lW, const float* __restrict__ lb,
  float* __restrict__ out)
{
  const int b = blockIdx.x, t = threadIdx.x;
  __shared__ float rn[E], hn[E], hid1[E], hid2[128];
  if (t<E){ rn[t]=rn_cap[b*E+t]; hn[t]=hn_cap[b*E+t]; }
  __syncthreads();
  if (t<E){
    float a0=0,a1=0;
    #pragma unroll
    for (int k=0;k<E;++k){
      a0 += rn[k]*wp[k*E+t];
      a1 += hn[k]*wx[k*E+t];
    }
    hid1[t] = tanh_fast(a0+a1);
  }
  __syncthreads();
  {
    float acc = l1b[t];
    #pragma unroll
    for (int k=0;k<E;++k) acc += hid1[k]*l1W[t*E+k];
    hid2[t] = tanh_fast(acc);
  }
  __syncthreads();
  if (t<4){
    float acc = lb[t];
    #pragma unroll
    for (int k=0;k<128;++k) acc += hid2[k]*lW[t*128+k];
    out[b*4+t] = acc;
  }
}

extern "C" void kernel_launch(void* const* d_in, const int* in_sizes, int n_in,
                              void* d_out, int out_size, void* d_ws, size_t ws_size,
                              hipStream_t stream)
{
  const int*   sent1 = (const int*)  d_in[0];
  const int*   sent2 = (const int*)  d_in[1];
  const int*   s1len = (const int*)  d_in[2];
  const int*   s2len = (const int*)  d_in[3];
  const float* s1s   = (const float*)d_in[4];
  const float* emb   = (const float*)d_in[6];
  const float* Wih1  = (const float*)d_in[7];
  const float* Whh1  = (const float*)d_in[8];
  const float* bih1  = (const float*)d_in[9];
  const float* bhh1  = (const float*)d_in[10];
  const float* Wih2  = (const float*)d_in[11];
  const float* Whh2  = (const float*)d_in[12];
  const float* bih2  = (const float*)d_in[13];
  const float* bhh2  = (const float*)d_in[14];
  const float* wy    = (const float*)d_in[15];
  const float* wh    = (const float*)d_in[16];
  const float* w     = (const float*)d_in[17];
  const float* wp    = (const float*)d_in[18];
  const float* wx    = (const float*)d_in[19];
  const float* wr    = (const float*)d_in[20];
  const float* wt    = (const float*)d_in[21];
  const float* l1W   = (const float*)d_in[22];
  const float* l1b   = (const float*)d_in[23];
  const float* lW    = (const float*)d_in[24];
  const float* lb    = (const float*)d_in[25];
  float* out = (float*)d_out;

  float* ws  = (float*)d_ws;
  float* gx1 = ws;                         // 64*384*256 = 6291456 floats
  float* gx2 = gx1 + 6291456;
  float* h1  = gx2 + 6291456;              // 64*384*64 = 1572864
  float* outa= h1  + 1572864;
  float* Eg  = outa + 1572864;
  float* Hwr = Eg  + 1572864;
  float* Hwt = Hwr + 1572864;
  float* rnc = Hwt + 1572864;              // 4096
  float* hnc = rnc + 4096;
  // gx1 is dead after lstm_kernel -> reuse for capture buffers
  float* exCapT = gx1;                     // 64*64*384 = 1572864
  float* TCap   = gx1 + 1572864;           // 64*64*64  = 262144

  hipLaunchKernelGGL(gx_kernel, dim3(512), dim3(256), 0, stream,
    sent1, sent2, emb, Wih1, bih1, bhh1, Wih2, bih2, bhh2, gx1, gx2);
  hipLaunchKernelGGL(lstm_kernel, dim3(64), dim3(256), 0, stream,
    gx1, gx2, Whh1, Whh2, s1len, s2len, h1, outa, hnc);
  hipLaunchKernelGGL(base_kernel, dim3(3072), dim3(256), 0, stream,
    h1, outa, wy, wh, wr, wt, Eg, Hwr, Hwt);
  hipLaunchKernelGGL(attn_kernel, dim3(64), dim3(768), 0, stream,
    Eg, Hwr, Hwt, w, wr, wt, s1s, s2len, exCapT, TCap);
  hipLaunchKernelGGL(capfix_kernel, dim3(64), dim3(256), 0, stream,
    h1, s2len, exCapT, TCap, rnc);
  hipLaunchKernelGGL(final_kernel, dim3(64), dim3(128), 0, stream,
    rnc, hnc, wp, wx, l1W, l1b, lW, lb, out);
}

// Round 9
// 2983.213 us; speedup vs baseline: 1.0008x; 1.0008x over previous
//
#include <hip/hip_runtime.h>

#define E 64
#define D 50
#define SS 384
#define G4 256   // 4*E

__device__ __forceinline__ float fast_rcp(float x){ return __builtin_amdgcn_rcpf(x); }
__device__ __forceinline__ float tanh_fast(float x){
  // tanh(x) = 1 - 2/(exp(2x)+1)
  float e = __expf(2.0f*x);
  return 1.0f - 2.0f*fast_rcp(e + 1.0f);
}
__device__ __forceinline__ float sigmoid_fast(float x){
  return fast_rcp(1.0f + __expf(-x));
}
// whole-wave rotate via DPP (VALU pipe). wave_ror:1: lane i <- lane (i-1)&63.
__device__ __forceinline__ float ror1(float x){
  return __int_as_float(__builtin_amdgcn_update_dpp(
      0, __float_as_int(x), 0x13C /*wave_ror:1*/, 0xF, 0xF, false));
}
__device__ __forceinline__ float rdlane(float v, int l){
  return __int_as_float(__builtin_amdgcn_readlane(__float_as_int(v), l));
}

// ---------------------------------------------------------------------------
// K0: gx[b,s,j] = bias[j] + sum_k emb[sent[b,s],k] * Wih[j,k]   (both LSTMs)
// ---------------------------------------------------------------------------
__global__ __launch_bounds__(256, 1) void gx_kernel(
  const int* __restrict__ sent1, const int* __restrict__ sent2,
  const float* __restrict__ emb,
  const float* __restrict__ Wih1, const float* __restrict__ bih1, const float* __restrict__ bhh1,
  const float* __restrict__ Wih2, const float* __restrict__ bih2, const float* __restrict__ bhh2,
  float* __restrict__ gx1, float* __restrict__ gx2)
{
  const int bb    = blockIdx.x;     // 0..511
  const int which = bb >> 8;
  const int chunk = bb & 255;
  const int j     = threadIdx.x;
  const int*   sent = which ? sent2 : sent1;
  const float* Wih  = which ? Wih2  : Wih1;
  const float* bA   = which ? bih2  : bih1;
  const float* bB   = which ? bhh2  : bhh1;
  float*       gx   = which ? gx2   : gx1;

  float wih[D];
  #pragma unroll
  for (int k=0;k<D;k+=2){
    float2 v = *(const float2*)&Wih[j*D+k];
    wih[k]=v.x; wih[k+1]=v.y;
  }
  const float bias = bA[j] + bB[j];

  __shared__ __align__(16) float xb[8][52];
  const int row0 = chunk*96;
  for (int c=0;c<12;++c){
    const int r0 = row0 + c*8;
    #pragma unroll
    for (int q=0;q<2;++q){
      int tt = j + q*256;
      if (tt < 400){
        int r = tt/50;
        int k = tt - r*50;
        int idx = sent[r0 + r];
        xb[r][k] = emb[(size_t)idx*D + k];
      }
    }
    __syncthreads();
    for (int r=0;r<8;++r){
      float a0=bias, a1=0.f;
      #pragma unroll
      for (int k=0;k<48;k+=4){
        float4 xv = *(const float4*)&xb[r][k];
        a0 += xv.x*wih[k]   + xv.y*wih[k+1];
        a1 += xv.z*wih[k+2] + xv.w*wih[k+3];
      }
      a0 += xb[r][48]*wih[48];
      a1 += xb[r][49]*wih[49];
      gx[(size_t)(r0+r)*G4 + j] = a0+a1;
    }
    __syncthreads();
  }
}

// ---------------------------------------------------------------------------
// K1: both LSTM recurrences. 64 blocks x 256 threads (4 waves).
// DPP rotate-MAC (verified r4). whht[64]+misc ~80 live fits default budget.
// ---------------------------------------------------------------------------
__global__ __launch_bounds__(256, 1) void lstm_kernel(
  const float* __restrict__ gx1, const float* __restrict__ gx2,
  const float* __restrict__ Whh1, const float* __restrict__ Whh2,
  const int* __restrict__ s1_len, const int* __restrict__ s2_len,
  float* __restrict__ h1_all, float* __restrict__ out_all,
  float* __restrict__ hn_cap)
{
  const int b = blockIdx.x;
  const int j = threadIdx.x;
  const int lane = j & 63;
  const int wv = j >> 6;
  __shared__ float h_lds[64];
  __shared__ float gates[256];

  float whht[64];                       // whht[i] = Whh[j][(lane-i)&63] (ror direction)
  #pragma unroll
  for (int i=0;i<32;++i){
    whht[i]    = Whh1[j*64 + ((lane-i)&63)];
    whht[i+32] = Whh1[j*64 + ((lane-i+32)&63)];
  }

  const int is_g = (wv==2);             // wave-uniform: gate 'g' uses tanh
  float c_reg=0.f, gh=0.f, gc=0.f, hn=0.f;
  int idx1=0, idx2=0;
  if (j<64){ idx1=s1_len[b*64+j]; idx2=s2_len[b*64+j]; h_lds[j]=0.f; }
  __syncthreads();

  // ---- LSTM1 ----
  {
    const float* gx = gx1 + (size_t)b*SS*G4;
    float* hout = h1_all + (size_t)b*SS*E;
    float gx_cur = gx[j];
    float gx_n1  = gx[G4 + j];
    for (int s=0;s<SS;++s){
      int sn2 = (s+2<SS)? s+2 : SS-1;
      float gx_n2 = gx[(size_t)sn2*G4 + j];
      float hr  = h_lds[lane];          // iter i holds h[(lane-i)&63]
      float hr2 = h_lds[lane^32];       // iter i holds h[(lane-i+32)&63]
      float g0 = gx_cur, g1 = 0.f;
      #pragma unroll
      for (int i=0;i<32;++i){
        g0 = __builtin_fmaf(hr,  whht[i],    g0);
        g1 = __builtin_fmaf(hr2, whht[i+32], g1);
        hr = ror1(hr); hr2 = ror1(hr2);
      }
      float g = g0 + g1;
      gates[j] = is_g ? tanh_fast(g) : sigmoid_fast(g);
      __syncthreads();
      if (j<64){
        float gi=gates[j], gf=gates[64+j], gg=gates[128+j], go=gates[192+j];
        c_reg = gf*c_reg + gi*gg;
        float h = go * tanh_fast(c_reg);
        h_lds[j] = h;
        hout[(size_t)s*E + j] = h;
        if (s==idx1){ gh=h; gc=c_reg; }
      }
      gx_cur = gx_n1; gx_n1 = gx_n2;
      __syncthreads();
    }
  }
  // ---- LSTM2 ----
  #pragma unroll
  for (int i=0;i<32;++i){
    whht[i]    = Whh2[j*64 + ((lane-i)&63)];
    whht[i+32] = Whh2[j*64 + ((lane-i+32)&63)];
  }
  if (j<64){ h_lds[j]=gh; c_reg=gc; }
  __syncthreads();
  {
    const float* gx = gx2 + (size_t)b*SS*G4;
    float* hout = out_all + (size_t)b*SS*E;
    float gx_cur = gx[j];
    float gx_n1  = gx[G4 + j];
    for (int s=0;s<SS;++s){
      int sn2 = (s+2<SS)? s+2 : SS-1;
      float gx_n2 = gx[(size_t)sn2*G4 + j];
      float hr  = h_lds[lane];
      float hr2 = h_lds[lane^32];
      float g0 = gx_cur, g1 = 0.f;
      #pragma unroll
      for (int i=0;i<32;++i){
        g0 = __builtin_fmaf(hr,  whht[i],    g0);
        g1 = __builtin_fmaf(hr2, whht[i+32], g1);
        hr = ror1(hr); hr2 = ror1(hr2);
      }
      float g = g0 + g1;
      gates[j] = is_g ? tanh_fast(g) : sigmoid_fast(g);
      __syncthreads();
      if (j<64){
        float gi=gates[j], gf=gates[64+j], gg=gates[128+j], go=gates[192+j];
        c_reg = gf*c_reg + gi*gg;
        float h = go * tanh_fast(c_reg);
        h_lds[j] = h;
        hout[(size_t)s*E + j] = h;
        if (s==idx2) hn = h;
      }
      gx_cur = gx_n1; gx_n1 = gx_n2;
      __syncthreads();
    }
  }
  if (j<64) hn_cap[b*64+j] = hn;
}

// ---------------------------------------------------------------------------
// K2: 3072 blocks. wac[64]+wbc[64] = 128 live -> needs budget > default
// squeeze: amdgpu_waves_per_eu(1,3) grants ~170 VGPRs, no spill.
// ---------------------------------------------------------------------------
__global__ __launch_bounds__(256)
__attribute__((amdgpu_waves_per_eu(1, 3)))
void base_kernel(
  const float* __restrict__ h1_all, const float* __restrict__ out_all,
  const float* __restrict__ wy, const float* __restrict__ wh,
  const float* __restrict__ wr, const float* __restrict__ wt,
  float* __restrict__ E_g, float* __restrict__ Hwr_g, float* __restrict__ Hwt_g)
{
  const int which = (blockIdx.x >= 1536);
  const int blk   = blockIdx.x - (which ? 1536 : 0);
  const int t = threadIdx.x;
  const int wave = t>>6, lane = t&63;
  const float* WA = which ? wr : wy;
  const float* WB = which ? wt : wh;
  float wac[E], wbc[E];
  #pragma unroll
  for (int e=0;e<E;++e){ wac[e]=WA[e*E+lane]; wbc[e]=WB[e*E+lane]; }
  const int row0 = blk*16 + wave*4;
  for (int r=0;r<4;++r){
    int row = row0 + r;
    float hv = h1_all[(size_t)row*E + lane];
    if (which){
      float a0=0,a1=0;
      #pragma unroll
      for (int e=0;e<E;++e){
        float hb = rdlane(hv,e);
        a0 += hb*wac[e];
        a1 += hb*wbc[e];
      }
      Hwr_g[(size_t)row*E + lane] = a0;
      Hwt_g[(size_t)row*E + lane] = a1;
    } else {
      float ov = out_all[(size_t)row*E + lane];
      float a0=0,a1=0;
      #pragma unroll
      for (int e=0;e<E;++e){
        a0 += rdlane(hv,e)*wac[e];
        a1 += rdlane(ov,e)*wbc[e];
      }
      E_g[(size_t)row*E + lane] = __expf(2.0f*(a0+a1));
    }
  }
}

// ---------------------------------------------------------------------------
// K3: attention scan. 64 blocks x 768 threads (12 waves), 384 steps,
// TWO barriers/step. Closed recurrence over (rw = r@wr, ri = r@wt) — r7/r8
// verified math. FIX vs r8: amdgpu_waves_per_eu(1,3) grants ~170-VGPR budget
// so Ee[32]+htWr[32]+htWt[32]+chunks (~116 live) stay in registers. r8's
// allocator squeezed to 84 VGPRs -> ~40 values spilled to scratch; the
// in-loop L2 reloads (dependent, ~200cyc) were the 2x step-time regression
// (FETCH/WRITE +7MB each = the 7.9MB scratch working set).
// Only 12 waves/CU ever resident (64 blocks) -> max-3-waves/EU costs nothing.
// ---------------------------------------------------------------------------
__global__ __launch_bounds__(768)
__attribute__((amdgpu_waves_per_eu(1, 3)))
void attn_kernel(
  const float* __restrict__ E_all, const float* __restrict__ Hwr_all,
  const float* __restrict__ Hwt_all,
  const float* __restrict__ w, const float* __restrict__ wr, const float* __restrict__ wt,
  const float* __restrict__ s1_s, const int* __restrict__ s2_len,
  float* __restrict__ exCapT,    // [b][slot<=63][row]  (coalesced stores)
  float* __restrict__ TCap)      // [b][slot][lane]
{
  const int b = blockIdx.x;
  const int t = threadIdx.x;
  const int wv = t>>6, lane = t&63;
  const int pair = wv>>1;          // 0..5: row group
  const int half = wv&1;           // e-range half
  const int off  = half*32;
  const int row  = pair*64 + lane;

  __shared__ float4 accP[12*64];   // {chainWr, chainWt, tot, -} per wave
  __shared__ float2 tgP[2][12*64]; // {T@wr partial, T@wt partial} per wave
  __shared__ float  scoreH[2][6*64];
  __shared__ unsigned int umask[12];

  const float* Eb   = E_all   + (size_t)b*SS*E;
  const float* HwrB = Hwr_all + (size_t)b*SS*E;
  const float* HwtB = Hwt_all + (size_t)b*SS*E;
  float* exCapB = exCapT + (size_t)b*64*SS;  // slot*SS + row
  float* TCapB  = TCap   + (size_t)b*64*64;  // slot*64 + lane

  // ---- preload (once) ----
  float Ee[32];                    // E[row][off..off+32)
  #pragma unroll
  for (int k=0;k<32;k+=4){
    float4 v = *(const float4*)&Eb[(size_t)row*E + off + k];
    Ee[k]=v.x; Ee[k+1]=v.y; Ee[k+2]=v.z; Ee[k+3]=v.w;
  }
  float htWr[32], htWt[32];        // rotate-chain tables (r6-verified pattern)
  #pragma unroll
  for (int i=0;i<32;++i){
    int rr = pair*64 + ((lane-i+off)&63);
    htWr[i] = HwrB[(size_t)rr*E + lane];
    htWt[i] = HwtB[(size_t)rr*E + lane];
  }
  float WSUM = 0.f;
  for (int e=0;e<64;++e) WSUM += w[e];     // uniform -> scalar
  const float s1v = s1_s[b*SS + row];
  const int  idx2 = s2_len[b*E + lane];
  // GEMV k-chunk for this wave (T@wr, T@wt): 4x6 + 8x5 = 64
  const int k0  = (wv<4)? wv*6 : 24+(wv-4)*5;
  const int cnt = (wv<4)? 6 : 5;
  float wrch[6], wtch[6];
  #pragma unroll
  for (int jj=0;jj<6;++jj){
    int kk = k0 + ((jj<cnt)? jj : 0);
    wrch[jj] = wr[kk*E + lane];
    wtch[jj] = wt[kk*E + lane];
  }

  // ---- init: r0 = 0 -> chains 0, tot 1 (one wave), tgP[0] = 0; mask ----
  accP[wv*64+lane] = make_float4(0.f, 0.f, (wv==0)?1.f:0.f, 0.f);
  tgP[0][wv*64+lane] = make_float2(0.f, 0.f);
  if (t<12) umask[t] = 0u;
  __syncthreads();
  if (wv==0) atomicOr(&umask[idx2>>5], 1u<<(idx2&31));
  __syncthreads();

  int slot = 0;
  for (int s=0;s<SS;++s){
    const bool need = (umask[s>>5]>>(s&31)) & 1u;

    // ---- phase 1: combine prev partials; score-half; T-GEMV ----
    float cWr=0.f, cWt=0.f, tot=0.f;
    #pragma unroll
    for (int q=0;q<12;++q){
      float4 v = accP[q*64+lane];
      cWr+=v.x; cWt+=v.y; tot+=v.z;
    }
    float twr=0.f, twt=0.f;
    #pragma unroll
    for (int q=0;q<12;++q){
      float2 v = tgP[s&1][q*64+lane];
      twr+=v.x; twt+=v.y;
    }
    float inv = fast_rcp(tot);
    float rw = __builtin_fmaf(cWr, inv, twr);   // rw[e=lane]
    float ri = __builtin_fmaf(cWt, inv, twt);   // ri[e=lane]
    float Rl = __expf(2.0f*rw);
    float T  = tanh_fast(ri);
    if (need && wv==0) TCapB[slot*64 + lane] = T;

    // score-half (r6-verified loop)
    float sc0=0.f, sc1=0.f, sc2=0.f, sc3=0.f;
    #pragma unroll
    for (int k=0;k<32;k+=4){
      float r0=rdlane(Rl,off+k),   r1=rdlane(Rl,off+k+1);
      float r2=rdlane(Rl,off+k+2), r3=rdlane(Rl,off+k+3);
      sc0 = __builtin_fmaf(w[off+k],   fast_rcp(__builtin_fmaf(Ee[k],  r0,1.f)), sc0);
      sc1 = __builtin_fmaf(w[off+k+1], fast_rcp(__builtin_fmaf(Ee[k+1],r1,1.f)), sc1);
      sc2 = __builtin_fmaf(w[off+k+2], fast_rcp(__builtin_fmaf(Ee[k+2],r2,1.f)), sc2);
      sc3 = __builtin_fmaf(w[off+k+3], fast_rcp(__builtin_fmaf(Ee[k+3],r3,1.f)), sc3);
    }
    float myh = (sc0+sc1)+(sc2+sc3);
    scoreH[half][pair*64+lane] = myh;

    // T-GEMV partials for NEXT step (input T known now)
    {
      float rwp=0.f, rtp=0.f;
      #pragma unroll
      for (int jj=0;jj<6;++jj){
        if (jj<cnt){
          float rv = rdlane(T, k0+jj);
          rwp = __builtin_fmaf(rv, wrch[jj], rwp);
          rtp = __builtin_fmaf(rv, wtch[jj], rtp);
        }
      }
      tgP[(s+1)&1][wv*64+lane] = make_float2(rwp, rtp);
    }
    __syncthreads();

    // ---- phase 2: combine halves; ex; dual rotate-MAC chain ----
    float oth = scoreH[1-half][pair*64+lane];
    float sc = WSUM - 2.0f*(myh + oth);
    float masked = s1v*sc - (1.f - s1v)*1e12f;
    float ex = __expf(masked);
    if (need && half==0) exCapB[(size_t)slot*SS + row] = ex;  // coalesced

    float exr = half ? __shfl_xor(ex, 32) : ex;
    float aWr=0.f, aWt=0.f, at=0.f;
    #pragma unroll
    for (int i=0;i<32;++i){
      aWr = __builtin_fmaf(exr, htWr[i], aWr);
      aWt = __builtin_fmaf(exr, htWt[i], aWt);
      at += exr;
      exr = ror1(exr);
    }
    accP[wv*64+lane] = make_float4(aWr, aWt, at, 0.f);
    __syncthreads();

    slot += need ? 1 : 0;
  }
}

// ---------------------------------------------------------------------------
// K3b: capfix. 64 blocks x 256 threads. rn[lane] = (sum_row ex*h1)/tot + T.
// Transposes exCap[slot][rows] through padded LDS: coalesced float4 global
// loads; per-lane gather at slot c is conflict-free via stride 129.
// ---------------------------------------------------------------------------
__global__ __launch_bounds__(256, 1) void capfix_kernel(
  const float* __restrict__ h1_all, const int* __restrict__ s2_len,
  const float* __restrict__ exCapT, const float* __restrict__ TCap,
  float* __restrict__ rn_cap)
{
  const int b = blockIdx.x, t = threadIdx.x;
  const int wv = t>>6, lane = t&63;
  __shared__ unsigned int umask[12];
  __shared__ float exL[64*129];       // [slot][row-in-chunk], pad 129
  __shared__ float2 part[4][64];
  if (t<12) umask[t]=0u;
  __syncthreads();
  const int sl = s2_len[b*E + lane];
  if (wv==0) atomicOr(&umask[sl>>5], 1u<<(sl&31));
  __syncthreads();
  int c = 0;
  #pragma unroll
  for (int wdi=0; wdi<12; ++wdi){
    unsigned int wd = umask[wdi];
    unsigned int keep = (wdi < (sl>>5)) ? wd
                       : ((wdi == (sl>>5)) ? (wd & ((sl&31) ? ((1u<<(sl&31))-1u) : 0u)) : 0u);
    c += __popc(keep);
  }
  const float* h1b = h1_all + (size_t)b*SS*E;
  const float* exB = exCapT + (size_t)b*64*SS;
  float pa=0.f, pt=0.f;
  for (int chunk=0; chunk<3; ++chunk){
    const int base = chunk*128;
    // coalesced: exB[slot][base..base+127] -> exL[slot][r]
    for (int i=t; i<64*32; i+=256){
      int slot = i>>5;
      int r4   = (i&31)*4;
      float4 v = *(const float4*)&exB[(size_t)slot*SS + base + r4];
      exL[slot*129 + r4+0]=v.x; exL[slot*129 + r4+1]=v.y;
      exL[slot*129 + r4+2]=v.z; exL[slot*129 + r4+3]=v.w;
    }
    __syncthreads();
    const int woff = wv*32;
    #pragma unroll
    for (int i=0;i<32;++i){
      int r = woff + i;
      float exv = exL[c*129 + r];
      float hv  = h1b[(size_t)(base+r)*E + lane];
      pa = __builtin_fmaf(exv, hv, pa);
      pt += exv;
    }
    __syncthreads();
  }
  part[wv][lane] = make_float2(pa, pt);
  __syncthreads();
  if (wv==0){
    float av=0.f, tv=0.f;
    #pragma unroll
    for (int q=0;q<4;++q){ float2 v=part[q][lane]; av+=v.x; tv+=v.y; }
    rn_cap[b*E+lane] = av*fast_rcp(tv) + TCap[(size_t)b*64*64 + c*64 + lane];
  }
}

// ---------------------------------------------------------------------------
// K4: final MLP. 64 blocks x 128 threads.
// ---------------------------------------------------------------------------
__global__ __launch_bounds__(128, 1) void final_kernel(
  const float* __restrict__ rn_cap, const float* __restrict__ hn_cap,
  const float* __restrict__ wp, const float* __restrict__ wx,
  const float* __restrict__ l1W, const float* __restrict__ l1b,
  const float* __restrict__ lW, const float* __restrict__ lb,
  float* __restrict__ out)
{
  const int b = blockIdx.x, t = threadIdx.x;
  __shared__ float rn[E], hn[E], hid1[E], hid2[128];
  if (t<E){ rn[t]=rn_cap[b*E+t]; hn[t]=hn_cap[b*E+t]; }
  __syncthreads();
  if (t<E){
    float a0=0,a1=0;
    #pragma unroll
    for (int k=0;k<E;++k){
      a0 += rn[k]*wp[k*E+t];
      a1 += hn[k]*wx[k*E+t];
    }
    hid1[t] = tanh_fast(a0+a1);
  }
  __syncthreads();
  {
    float acc = l1b[t];
    #pragma unroll
    for (int k=0;k<E;++k) acc += hid1[k]*l1W[t*E+k];
    hid2[t] = tanh_fast(acc);
  }
  __syncthreads();
  if (t<4){
    float acc = lb[t];
    #pragma unroll
    for (int k=0;k<128;++k) acc += hid2[k]*lW[t*128+k];
    out[b*4+t] = acc;
  }
}

extern "C" void kernel_launch(void* const* d_in, const int* in_sizes, int n_in,
                              void* d_out, int out_size, void* d_ws, size_t ws_size,
                              hipStream_t stream)
{
  const int*   sent1 = (const int*)  d_in[0];
  const int*   sent2 = (const int*)  d_in[1];
  const int*   s1len = (const int*)  d_in[2];
  const int*   s2len = (const int*)  d_in[3];
  const float* s1s   = (const float*)d_in[4];
  const float* emb   = (const float*)d_in[6];
  const float* Wih1  = (const float*)d_in[7];
  const float* Whh1  = (const float*)d_in[8];
  const float* bih1  = (const float*)d_in[9];
  const float* bhh1  = (const float*)d_in[10];
  const float* Wih2  = (const float*)d_in[11];
  const float* Whh2  = (const float*)d_in[12];
  const float* bih2  = (const float*)d_in[13];
  const float* bhh2  = (const float*)d_in[14];
  const float* wy    = (const float*)d_in[15];
  const float* wh    = (const float*)d_in[16];
  const float* w     = (const float*)d_in[17];
  const float* wp    = (const float*)d_in[18];
  const float* wx    = (const float*)d_in[19];
  const float* wr    = (const float*)d_in[20];
  const float* wt    = (const float*)d_in[21];
  const float* l1W   = (const float*)d_in[22];
  const float* l1b   = (const float*)d_in[23];
  const float* lW    = (const float*)d_in[24];
  const float* lb    = (const float*)d_in[25];
  float* out = (float*)d_out;

  float* ws  = (float*)d_ws;
  float* gx1 = ws;                         // 64*384*256 = 6291456 floats
  float* gx2 = gx1 + 6291456;
  float* h1  = gx2 + 6291456;              // 64*384*64 = 1572864
  float* outa= h1  + 1572864;
  float* Eg  = outa + 1572864;
  float* Hwr = Eg  + 1572864;
  float* Hwt = Hwr + 1572864;
  float* rnc = Hwt + 1572864;              // 4096
  float* hnc = rnc + 4096;
  // gx1 is dead after lstm_kernel -> reuse for capture buffers
  float* exCapT = gx1;                     // 64*64*384 = 1572864
  float* TCap   = gx1 + 1572864;           // 64*64*64  = 262144

  hipLaunchKernelGGL(gx_kernel, dim3(512), dim3(256), 0, stream,
    sent1, sent2, emb, Wih1, bih1, bhh1, Wih2, bih2, bhh2, gx1, gx2);
  hipLaunchKernelGGL(lstm_kernel, dim3(64), dim3(256), 0, stream,
    gx1, gx2, Whh1, Whh2, s1len, s2len, h1, outa, hnc);
  hipLaunchKernelGGL(base_kernel, dim3(3072), dim3(256), 0, stream,
    h1, outa, wy, wh, wr, wt, Eg, Hwr, Hwt);
  hipLaunchKernelGGL(attn_kernel, dim3(64), dim3(768), 0, stream,
    Eg, Hwr, Hwt, w, wr, wt, s1s, s2len, exCapT, TCap);
  hipLaunchKernelGGL(capfix_kernel, dim3(64), dim3(256), 0, stream,
    h1, s2len, exCapT, TCap, rnc);
  hipLaunchKernelGGL(final_kernel, dim3(64), dim3(128), 0, stream,
    rnc, hnc, wp, wx, l1W, l1b, lW, lb, out);
}

// Round 10
// 1722.822 us; speedup vs baseline: 1.7330x; 1.7316x over previous
//
#include <hip/hip_runtime.h>

#define E 64
#define D 50
#define SS 384
#define G4 256   // 4*E

__device__ __forceinline__ float fast_rcp(float x){ return __builtin_amdgcn_rcpf(x); }
__device__ __forceinline__ float tanh_fast(float x){
  // tanh(x) = 1 - 2/(exp(2x)+1)
  float e = __expf(2.0f*x);
  return 1.0f - 2.0f*fast_rcp(e + 1.0f);
}
__device__ __forceinline__ float sigmoid_fast(float x){
  return fast_rcp(1.0f + __expf(-x));
}
// whole-wave rotate via DPP (VALU pipe). wave_ror:1: lane i <- lane (i-1)&63.
__device__ __forceinline__ float ror1(float x){
  return __int_as_float(__builtin_amdgcn_update_dpp(
      0, __float_as_int(x), 0x13C /*wave_ror:1*/, 0xF, 0xF, false));
}
__device__ __forceinline__ float rdlane(float v, int l){
  return __int_as_float(__builtin_amdgcn_readlane(__float_as_int(v), l));
}

// ---------------------------------------------------------------------------
// K0: gx[b,s,j] = bias[j] + sum_k emb[sent[b,s],k] * Wih[j,k]   (both LSTMs)
// ---------------------------------------------------------------------------
__global__ __launch_bounds__(256, 1) void gx_kernel(
  const int* __restrict__ sent1, const int* __restrict__ sent2,
  const float* __restrict__ emb,
  const float* __restrict__ Wih1, const float* __restrict__ bih1, const float* __restrict__ bhh1,
  const float* __restrict__ Wih2, const float* __restrict__ bih2, const float* __restrict__ bhh2,
  float* __restrict__ gx1, float* __restrict__ gx2)
{
  const int bb    = blockIdx.x;     // 0..511
  const int which = bb >> 8;
  const int chunk = bb & 255;
  const int j     = threadIdx.x;
  const int*   sent = which ? sent2 : sent1;
  const float* Wih  = which ? Wih2  : Wih1;
  const float* bA   = which ? bih2  : bih1;
  const float* bB   = which ? bhh2  : bhh1;
  float*       gx   = which ? gx2   : gx1;

  float wih[D];
  #pragma unroll
  for (int k=0;k<D;k+=2){
    float2 v = *(const float2*)&Wih[j*D+k];
    wih[k]=v.x; wih[k+1]=v.y;
  }
  const float bias = bA[j] + bB[j];

  __shared__ __align__(16) float xb[8][52];
  const int row0 = chunk*96;
  for (int c=0;c<12;++c){
    const int r0 = row0 + c*8;
    #pragma unroll
    for (int q=0;q<2;++q){
      int tt = j + q*256;
      if (tt < 400){
        int r = tt/50;
        int k = tt - r*50;
        int idx = sent[r0 + r];
        xb[r][k] = emb[(size_t)idx*D + k];
      }
    }
    __syncthreads();
    for (int r=0;r<8;++r){
      float a0=bias, a1=0.f;
      #pragma unroll
      for (int k=0;k<48;k+=4){
        float4 xv = *(const float4*)&xb[r][k];
        a0 += xv.x*wih[k]   + xv.y*wih[k+1];
        a1 += xv.z*wih[k+2] + xv.w*wih[k+3];
      }
      a0 += xb[r][48]*wih[48];
      a1 += xb[r][49]*wih[49];
      gx[(size_t)(r0+r)*G4 + j] = a0+a1;
    }
    __syncthreads();
  }
}

// ---------------------------------------------------------------------------
// K1: both LSTM recurrences. 64 blocks x 256 threads (4 waves).
// v2: ONE barrier/step. h and c maintained redundantly IN REGISTERS by all
// 4 waves (h2 = shfl_xor(h,32); (lane+32)&63 == lane^32 keeps the verified
// r4 rotate-chain indexing). Gates exchanged via double-buffered LDS:
// write gates[s&1][j] -> barrier -> read 4 gate values -> update h/c.
// Buffer parity makes step s+2's write safely ordered after step s's reads
// (separated by the s+1 barrier). No h_lds, no wave0-only serial section.
// ---------------------------------------------------------------------------
__global__ __launch_bounds__(256, 1) void lstm_kernel(
  const float* __restrict__ gx1, const float* __restrict__ gx2,
  const float* __restrict__ Whh1, const float* __restrict__ Whh2,
  const int* __restrict__ s1_len, const int* __restrict__ s2_len,
  float* __restrict__ h1_all, float* __restrict__ out_all,
  float* __restrict__ hn_cap)
{
  const int b = blockIdx.x;
  const int j = threadIdx.x;
  const int lane = j & 63;
  const int wv = j >> 6;
  __shared__ float gates[2][256];

  float whht[64];                       // whht[i] = Whh[j][(lane-i)&63] (ror direction)
  #pragma unroll
  for (int i=0;i<32;++i){
    whht[i]    = Whh1[j*64 + ((lane-i)&63)];
    whht[i+32] = Whh1[j*64 + ((lane-i+32)&63)];
  }

  const int is_g = (wv==2);             // wave-uniform: gate 'g' uses tanh
  float c_reg=0.f, h=0.f, h2=0.f;
  float gh=0.f, gc=0.f, hn=0.f;
  const int idx1 = s1_len[b*64+lane];   // same value for all waves of a lane
  const int idx2 = s2_len[b*64+lane];

  // ---- LSTM1 ----
  {
    const float* gx = gx1 + (size_t)b*SS*G4;
    float* hout = h1_all + (size_t)b*SS*E;
    float gx_cur = gx[j];
    float gx_n1  = gx[G4 + j];
    for (int s=0;s<SS;++s){
      int sn2 = (s+2<SS)? s+2 : SS-1;
      float gx_n2 = gx[(size_t)sn2*G4 + j];
      float hr  = h;                    // iter i holds h[(lane-i)&63]
      float hr2 = h2;                   // iter i holds h[(lane-i+32)&63]
      float g0 = gx_cur, g1 = 0.f;
      #pragma unroll
      for (int i=0;i<32;++i){
        g0 = __builtin_fmaf(hr,  whht[i],    g0);
        g1 = __builtin_fmaf(hr2, whht[i+32], g1);
        hr = ror1(hr); hr2 = ror1(hr2);
      }
      float g = g0 + g1;
      gates[s&1][j] = is_g ? tanh_fast(g) : sigmoid_fast(g);
      __syncthreads();
      float gi=gates[s&1][lane],     gf=gates[s&1][64+lane];
      float gg=gates[s&1][128+lane], go=gates[s&1][192+lane];
      c_reg = gf*c_reg + gi*gg;
      h  = go * tanh_fast(c_reg);
      h2 = __shfl_xor(h, 32);
      if (wv==0) hout[(size_t)s*E + lane] = h;
      if (s==idx1){ gh=h; gc=c_reg; }
      gx_cur = gx_n1; gx_n1 = gx_n2;
    }
  }
  // ---- LSTM2 (init = gathered state; all waves hold it in registers) ----
  #pragma unroll
  for (int i=0;i<32;++i){
    whht[i]    = Whh2[j*64 + ((lane-i)&63)];
    whht[i+32] = Whh2[j*64 + ((lane-i+32)&63)];
  }
  h = gh; c_reg = gc;
  h2 = __shfl_xor(h, 32);
  {
    const float* gx = gx2 + (size_t)b*SS*G4;
    float* hout = out_all + (size_t)b*SS*E;
    float gx_cur = gx[j];
    float gx_n1  = gx[G4 + j];
    for (int s=0;s<SS;++s){
      int sn2 = (s+2<SS)? s+2 : SS-1;
      float gx_n2 = gx[(size_t)sn2*G4 + j];
      float hr  = h;
      float hr2 = h2;
      float g0 = gx_cur, g1 = 0.f;
      #pragma unroll
      for (int i=0;i<32;++i){
        g0 = __builtin_fmaf(hr,  whht[i],    g0);
        g1 = __builtin_fmaf(hr2, whht[i+32], g1);
        hr = ror1(hr); hr2 = ror1(hr2);
      }
      float g = g0 + g1;
      gates[s&1][j] = is_g ? tanh_fast(g) : sigmoid_fast(g);
      __syncthreads();
      float gi=gates[s&1][lane],     gf=gates[s&1][64+lane];
      float gg=gates[s&1][128+lane], go=gates[s&1][192+lane];
      c_reg = gf*c_reg + gi*gg;
      h  = go * tanh_fast(c_reg);
      h2 = __shfl_xor(h, 32);
      if (wv==0) hout[(size_t)s*E + lane] = h;
      if (s==idx2) hn = h;
      gx_cur = gx_n1; gx_n1 = gx_n2;
    }
  }
  if (wv==0) hn_cap[b*64+lane] = hn;
}

// ---------------------------------------------------------------------------
// K2: E_g[row,f] = exp( 2*(h1[row]@wy + out[row]@wh)[f] )    (r5-verified)
// ---------------------------------------------------------------------------
__global__ __launch_bounds__(256, 1) void base_kernel(
  const float* __restrict__ h1_all, const float* __restrict__ out_all,
  const float* __restrict__ wy, const float* __restrict__ wh,
  float* __restrict__ E_g)
{
  const int t = threadIdx.x;
  const int wave = t>>6, lane = t&63;
  float wyc[E], whc[E];
  #pragma unroll
  for (int e=0;e<E;++e){ wyc[e]=wy[e*E+lane]; whc[e]=wh[e*E+lane]; }
  const int row0 = blockIdx.x*16 + wave*4;
  for (int r=0;r<4;++r){
    int row = row0 + r;
    float hv = h1_all[(size_t)row*E + lane];
    float ov = out_all[(size_t)row*E + lane];
    float a0=0,a1=0;
    #pragma unroll
    for (int e=0;e<E;++e){
      a0 += rdlane(hv,e)*wyc[e];
      a1 += rdlane(ov,e)*whc[e];
    }
    E_g[(size_t)row*E + lane] = __expf(2.0f*(a0+a1));
  }
}

// ---------------------------------------------------------------------------
// K3: attention scan — r5-verified structure (best measured: ~1000 us).
// 64 blocks x 384 threads (6 waves), 384 steps, 2 barriers/step.
// ---------------------------------------------------------------------------
__global__ __launch_bounds__(384, 1) void attn_kernel(
  const float* __restrict__ h1_all, const float* __restrict__ E_all,
  const float* __restrict__ w, const float* __restrict__ wr, const float* __restrict__ wt,
  const float* __restrict__ s1_s, const int* __restrict__ s2_len,
  float* __restrict__ rn_cap)
{
  const int b = blockIdx.x;
  const int t = threadIdx.x;
  const int wv = t>>6, lane = t&63;
  const int row = wv*64 + lane;

  __shared__ float2 accP[6*64];    // {acc[e]-partial, tot-partial} per wave
  __shared__ float2 rwrtP[6*64];   // {rw-partial, rt-partial} per wave

  const float* h1b = h1_all + (size_t)b*SS*E;
  const float* Eb  = E_all  + (size_t)b*SS*E;

  // ---- preload (once) ----
  float Ee[64];                               // E row for my s-row
  #pragma unroll
  for (int k=0;k<64;k+=4){
    float4 v = *(const float4*)&Eb[(size_t)row*E + k];
    Ee[k]=v.x; Ee[k+1]=v.y; Ee[k+2]=v.z; Ee[k+3]=v.w;
  }
  float ht[64];                               // ht[i] = h[row (lane-i)&63][lane]
  #pragma unroll
  for (int i=0;i<32;++i){
    ht[i]    = h1b[(size_t)(wv*64 + ((lane-i)&63))*E + lane];
    ht[i+32] = h1b[(size_t)(wv*64 + ((lane-i+32)&63))*E + lane];
  }
  float WSUM = 0.f;
  for (int e=0;e<64;++e) WSUM += w[e];        // uniform -> scalar
  const float s1v = s1_s[b*SS + row];
  const int  idx2 = s2_len[b*E + lane];
  // GEMV k-chunk for this wave (rnew@wr, rnew@wt)
  const int k0  = (wv<4)? wv*11 : 44+(wv-4)*10;
  const int cnt = (wv<4)? 11 : 10;
  float wrch[11], wtch[11];
  #pragma unroll
  for (int jj=0;jj<11;++jj){
    int kk = k0 + ((jj<cnt)? jj : 0);
    wrch[jj] = wr[kk*E + lane];
    wtch[jj] = wt[kk*E + lane];
  }

  rwrtP[t] = make_float2(0.f, 0.f);   // r0 = 0 -> rw=0, rt=0
  __syncthreads();

  float rn_keep = 0.f;
  for (int s=0;s<SS;++s){
    // ---- A-pre: reduce rw/rt partials (redundant per wave, 6 b64 reads) ----
    float rwl=0.f, rtl=0.f;
    #pragma unroll
    for (int q=0;q<6;++q){ float2 v = rwrtP[q*64+lane]; rwl+=v.x; rtl+=v.y; }
    float Rl = __expf(2.0f*rwl);      // R[e=lane]

    // ---- score (thread-local over e; w[e] is a scalar operand) ----
    float sc0=0.f, sc1=0.f, sc2=0.f, sc3=0.f;
    #pragma unroll
    for (int e=0;e<64;e+=4){
      float r0=rdlane(Rl,e),   r1=rdlane(Rl,e+1);
      float r2=rdlane(Rl,e+2), r3=rdlane(Rl,e+3);
      sc0 = __builtin_fmaf(w[e],   fast_rcp(__builtin_fmaf(Ee[e],  r0,1.f)), sc0);
      sc1 = __builtin_fmaf(w[e+1], fast_rcp(__builtin_fmaf(Ee[e+1],r1,1.f)), sc1);
      sc2 = __builtin_fmaf(w[e+2], fast_rcp(__builtin_fmaf(Ee[e+2],r2,1.f)), sc2);
      sc3 = __builtin_fmaf(w[e+3], fast_rcp(__builtin_fmaf(Ee[e+3],r3,1.f)), sc3);
    }
    float sc = WSUM - 2.0f*(((sc0+sc1)+(sc2+sc3)));
    float masked = s1v*sc - (1.f - s1v)*1e12f;
    float ex = __expf(masked);        // |sc| <= sum|w| ~ 51 -> fp32 safe

    // ---- rotate-MAC: acc[e=lane] += ex[row]*h[row][lane], tot += ex ----
    float exr  = ex;                  // iter i: ex[row (lane-i)&63]
    float exr2 = __shfl_xor(ex, 32);  // iter i: ex[row (lane-i+32)&63]
    float acc=0.f, tot=0.f;
    #pragma unroll
    for (int i=0;i<32;++i){
      acc = __builtin_fmaf(exr,  ht[i],    acc);
      acc = __builtin_fmaf(exr2, ht[i+32], acc);
      tot += exr + exr2;
      exr = ror1(exr); exr2 = ror1(exr2);
    }
    accP[wv*64+lane] = make_float2(acc, tot);
    __syncthreads();

    // ---- phase C: reduce acc/tot, rnew, distributed GEMV ----
    float av=0.f, tv=0.f;
    #pragma unroll
    for (int q=0;q<6;++q){ float2 v = accP[q*64+lane]; av+=v.x; tv+=v.y; }
    float rnew = __builtin_fmaf(av, fast_rcp(tv), tanh_fast(rtl));
    if (wv==0 && s==idx2) rn_keep = rnew;
    float rwp=0.f, rtp=0.f;
    #pragma unroll
    for (int jj=0;jj<11;++jj){
      if (jj<cnt){
        float rv = rdlane(rnew, k0+jj);
        rwp = __builtin_fmaf(rv, wrch[jj], rwp);
        rtp = __builtin_fmaf(rv, wtch[jj], rtp);
      }
    }
    rwrtP[wv*64+lane] = make_float2(rwp, rtp);
    __syncthreads();
  }
  if (wv==0) rn_cap[b*E + lane] = rn_keep;
}

// ---------------------------------------------------------------------------
// K4: final MLP. 64 blocks x 128 threads.
// ---------------------------------------------------------------------------
__global__ __launch_bounds__(128, 1) void final_kernel(
  const float* __restrict__ rn_cap, const float* __restrict__ hn_cap,
  const float* __restrict__ wp, const float* __restrict__ wx,
  const float* __restrict__ l1W, const float* __restrict__ l1b,
  const float* __restrict__ lW, const float* __restrict__ lb,
  float* __restrict__ out)
{
  const int b = blockIdx.x, t = threadIdx.x;
  __shared__ float rn[E], hn[E], hid1[E], hid2[128];
  if (t<E){ rn[t]=rn_cap[b*E+t]; hn[t]=hn_cap[b*E+t]; }
  __syncthreads();
  if (t<E){
    float a0=0,a1=0;
    #pragma unroll
    for (int k=0;k<E;++k){
      a0 += rn[k]*wp[k*E+t];
      a1 += hn[k]*wx[k*E+t];
    }
    hid1[t] = tanh_fast(a0+a1);
  }
  __syncthreads();
  {
    float acc = l1b[t];
    #pragma unroll
    for (int k=0;k<E;++k) acc += hid1[k]*l1W[t*E+k];
    hid2[t] = tanh_fast(acc);
  }
  __syncthreads();
  if (t<4){
    float acc = lb[t];
    #pragma unroll
    for (int k=0;k<128;++k) acc += hid2[k]*lW[t*128+k];
    out[b*4+t] = acc;
  }
}

extern "C" void kernel_launch(void* const* d_in, const int* in_sizes, int n_in,
                              void* d_out, int out_size, void* d_ws, size_t ws_size,
                              hipStream_t stream)
{
  const int*   sent1 = (const int*)  d_in[0];
  const int*   sent2 = (const int*)  d_in[1];
  const int*   s1len = (const int*)  d_in[2];
  const int*   s2len = (const int*)  d_in[3];
  const float* s1s   = (const float*)d_in[4];
  const float* emb   = (const float*)d_in[6];
  const float* Wih1  = (const float*)d_in[7];
  const float* Whh1  = (const float*)d_in[8];
  const float* bih1  = (const float*)d_in[9];
  const float* bhh1  = (const float*)d_in[10];
  const float* Wih2  = (const float*)d_in[11];
  const float* Whh2  = (const float*)d_in[12];
  const float* bih2  = (const float*)d_in[13];
  const float* bhh2  = (const float*)d_in[14];
  const float* wy    = (const float*)d_in[15];
  const float* wh    = (const float*)d_in[16];
  const float* w     = (const float*)d_in[17];
  const float* wp    = (const float*)d_in[18];
  const float* wx    = (const float*)d_in[19];
  const float* wr    = (const float*)d_in[20];
  const float* wt    = (const float*)d_in[21];
  const float* l1W   = (const float*)d_in[22];
  const float* l1b   = (const float*)d_in[23];
  const float* lW    = (const float*)d_in[24];
  const float* lb    = (const float*)d_in[25];
  float* out = (float*)d_out;

  float* ws  = (float*)d_ws;
  float* gx1 = ws;                         // 64*384*256 = 6291456 floats
  float* gx2 = gx1 + 6291456;
  float* h1  = gx2 + 6291456;              // 64*384*64 = 1572864
  float* outa= h1  + 1572864;
  float* Eg  = outa + 1572864;
  float* rnc = Eg  + 1572864;              // 4096
  float* hnc = rnc + 4096;

  hipLaunchKernelGGL(gx_kernel, dim3(512), dim3(256), 0, stream,
    sent1, sent2, emb, Wih1, bih1, bhh1, Wih2, bih2, bhh2, gx1, gx2);
  hipLaunchKernelGGL(lstm_kernel, dim3(64), dim3(256), 0, stream,
    gx1, gx2, Whh1, Whh2, s1len, s2len, h1, outa, hnc);
  hipLaunchKernelGGL(base_kernel, dim3(1536), dim3(256), 0, stream,
    h1, outa, wy, wh, Eg);
  hipLaunchKernelGGL(attn_kernel, dim3(64), dim3(384), 0, stream,
    h1, Eg, w, wr, wt, s1s, s2len, rnc);
  hipLaunchKernelGGL(final_kernel, dim3(64), dim3(128), 0, stream,
    rnc, hnc, wp, wx, l1W, l1b, lW, lb, out);
}